// Round 17
// baseline (2471.518 us; speedup 1.0000x reference)
//
#include <hip/hip_runtime.h>
#include <math.h>

#define N_NODES 16384
#define N_EDGES 262144
#define TOW 5
#define FI 75            // F_IN
#define FO 15            // F_OUT
#define DE 50
#define NL 4
#define NG 256
#define HWP 752          // padded node stride: [hWi 0..374][pad][hWj 376..750][pad]
#define ATS 16400        // aggT row stride in floats (16384 + 16: breaks 64KB aliasing)
#define ENB 8            // nodes per k_edge block (one 128-lane wave-pair each)

static __device__ __attribute__((aligned(16))) float g_hA[N_NODES*FI];
static __device__ __attribute__((aligned(16))) float g_hB[N_NODES*FI];
static __device__ __attribute__((aligned(16))) float g_hW[N_NODES*HWP];
static __device__ __attribute__((aligned(16))) float g_ec[NL*4*376];
static __device__ __attribute__((aligned(16))) float g_qwP[NL*TOW*3*300*16]; // padded repack
static __device__ int    g_deg[N_NODES];
static __device__ int    g_rowstart[N_NODES+1];
static __device__ int    g_cursor[N_NODES];
static __device__ int    g_edge[N_EDGES];
static __device__ double g_bns1[FI];
static __device__ double g_bns2[FI];
static __device__ float  g_pool[NG*FI];

__global__ void k_embed(const int* __restrict__ x, const float* __restrict__ node_emb) {
    int i = blockIdx.x * blockDim.x + threadIdx.x;
    if (i < N_NODES*FI) {
        int n = i / FI, f = i % FI;
        g_hA[i] = node_emb[x[n]*FI + f];
    }
}

__global__ void k_zerodeg() {
    int i = blockIdx.x * blockDim.x + threadIdx.x;
    if (i < N_NODES) g_deg[i] = 0;
}

__global__ void k_hist(const int* __restrict__ dst) {
    int e = blockIdx.x * blockDim.x + threadIdx.x;
    if (e < N_EDGES) atomicAdd(&g_deg[dst[e]], 1);
}

__global__ void k_scan() {
    __shared__ int part[1024];
    int t = threadIdx.x;
    int base = t * 16;
    int loc[16];
    int s = 0;
    #pragma unroll
    for (int i = 0; i < 16; i++) { loc[i] = s; s += g_deg[base + i]; }
    part[t] = s;
    __syncthreads();
    for (int off = 1; off < 1024; off <<= 1) {
        int v = 0;
        if (t >= off) v = part[t - off];
        __syncthreads();
        if (t >= off) part[t] += v;
        __syncthreads();
    }
    int excl = (t == 0) ? 0 : part[t - 1];
    #pragma unroll
    for (int i = 0; i < 16; i++) {
        g_rowstart[base + i] = excl + loc[i];
        g_cursor[base + i]   = excl + loc[i];
    }
    if (t == 1023) g_rowstart[N_NODES] = part[1023];
}

__global__ void k_scatter(const int* __restrict__ src, const int* __restrict__ dst,
                          const int* __restrict__ attr) {
    int e = blockIdx.x * blockDim.x + threadIdx.x;
    if (e < N_EDGES) {
        int d = dst[e];
        int pos = atomicAdd(&g_cursor[d], 1);
        g_edge[pos] = src[e] | (attr[e] << 16);
    }
}

// one-time repack of post_w into padded 16-float rows:
// g_qwP[(( (l*5+tw)*3 + s )*300 + k)*16 + g]
__global__ void k_wq(const float* __restrict__ post_w) {
    int i = blockIdx.x * blockDim.x + threadIdx.x;
    if (i < NL*TOW*900*FO) {
        int g = i % FO;
        int r = i / FO;
        int f = r % 900;
        int lt = r / 900;          // l*5+tw
        int s = f / 300, k = f % 300;
        g_qwP[((lt*3 + s)*300 + k)*16 + g] = post_w[i];
    }
}

// all-layer edge contribution tables: g_ec[l][a][376]
__global__ void k_ec(const float* __restrict__ edge_emb, const float* __restrict__ edge_enc_w,
                     const float* __restrict__ edge_enc_b, const float* __restrict__ pre_w,
                     const float* __restrict__ pre_b) {
    int l = blockIdx.x;
    const float* eew = edge_enc_w + l*DE*FI;
    const float* eeb = edge_enc_b + l*FI;
    const float* pw  = pre_w + l*TOW*3*FI*FI;
    const float* pb  = pre_b + l*TOW*FI;
    __shared__ float e_enc[4*FI];
    int t = threadIdx.x;
    if (t < 4*FI) {
        int a = t / FI, f = t % FI;
        float s = eeb[f];
        for (int d = 0; d < DE; d++) s += edge_emb[a*DE + d] * eew[d*FI + f];
        e_enc[t] = s;
    }
    __syncthreads();
    for (int o = t; o < 4*376; o += blockDim.x) {
        int a = o / 376;
        int r = o % 376;
        float s = 0.f;
        if (r < TOW*FI) {
            int tw = r / FI, g = r % FI;
            s = pb[tw*FI + g];
            const float* W = pw + (tw*(3*FI) + 2*FI)*FI + g;
            for (int f = 0; f < FI; f++) s += e_enc[a*FI + f] * W[f*FI];
        }
        g_ec[l*1504 + o] = s;
    }
}

// node transform; BN+ReLU of previous layer fused (mu/rsig from sums).
// Inner loop vectorized: one ds_read_b128 per node per f-quad (19 quads),
// 4 scalar weight loads per quad (w3=0 on the tail quad).
#define NPB 8
__global__ void k_hw(const float* __restrict__ pw, const float* __restrict__ gamma,
                     const float* __restrict__ beta, int first) {
    __shared__ __align__(16) float hsh[NPB][76];
    int n0 = blockIdx.x * NPB;
    int tid = threadIdx.x;
    for (int i = tid; i < NPB*76; i += blockDim.x) {
        int nn = i / 76, f = i % 76;
        float v = 0.f;
        if (f < FI) {
            int idx = (n0 + nn)*FI + f;
            if (first) {
                v = g_hA[idx];
            } else {
                double mud  = g_bns1[f] * (1.0/N_NODES);
                double vard = g_bns2[f] * (1.0/N_NODES) - mud*mud;
                if (vard < 0.0) vard = 0.0;
                float mu   = (float)mud;
                float rsig = (float)(1.0 / sqrt(vard + 1e-5));
                v = (g_hB[idx] - mu) * rsig * gamma[f] + beta[f];
                v = v > 0.f ? v : 0.f;
            }
        }
        hsh[nn][f] = v;
    }
    __syncthreads();
    for (int o = tid; o < 2*TOW*FI; o += blockDim.x) {
        int half = o / (TOW*FI);
        int r = o % (TOW*FI);
        int tw = r / FI, g = r % FI;
        const float* W = pw + (tw*(3*FI) + half*FI)*FI + g;
        float acc[NPB];
        #pragma unroll
        for (int nn = 0; nn < NPB; nn++) acc[nn] = 0.f;
        for (int fq = 0; fq < 19; ++fq) {
            int f = fq*4;
            float w0 = W[f*FI];
            float w1 = W[(f+1)*FI];
            float w2 = W[(f+2)*FI];
            float w3 = (fq < 18) ? W[(f+3)*FI] : 0.f;
            #pragma unroll
            for (int nn = 0; nn < NPB; nn++) {
                float4 h = *(const float4*)&hsh[nn][f];
                acc[nn] += h.x*w0 + h.y*w1 + h.z*w2 + h.w*w3;
            }
        }
        #pragma unroll
        for (int nn = 0; nn < NPB; nn++)
            g_hW[(n0+nn)*HWP + half*376 + r] = acc[nn];
    }
}

// per-node edge aggregation: one 128-lane wave-pair per node, ENB=8 nodes/block
// (1024 threads). Register accumulate; finalize into LDS tile; transpose-write
// channel-major aggT as 32B runs (normal stores -> L2 write-combining).
__global__ __launch_bounds__(128*ENB) void k_edge(int l, float* __restrict__ aggT) {
    __shared__ float aggl[ENB][1504];
    int tid = threadIdx.x;
    if (blockIdx.x == 0 && tid < FI) { g_bns1[tid] = 0.0; g_bns2[tid] = 0.0; }
    int wp  = tid >> 7;
    int q   = tid & 127;
    int n   = blockIdx.x * ENB + wp;
    bool act = q < 94;
    const float* ec = g_ec + l*1504;
    int e0 = g_rowstart[n], e1 = g_rowstart[n+1];
    int cnt = e1 - e0;

    float s0=0.f,s1=0.f,s2=0.f,s3=0.f;
    float t0=0.f,t1=0.f,t2=0.f,t3=0.f;
    float mn0=1e30f,mn1=1e30f,mn2=1e30f,mn3=1e30f;
    float mx0=-1e30f,mx1=-1e30f,mx2=-1e30f,mx3=-1e30f;
    float h0=0.f,h1=0.f,h2=0.f,h3=0.f;
    if (act) {
        float4 hv = *(const float4*)&g_hW[n*HWP + 4*q];
        h0=hv.x; h1=hv.y; h2=hv.z; h3=hv.w;
    }

    for (int e = e0; e < e1; e += 4) {
        int i1 = e+1, i2 = e+2, i3 = e+3;
        int pk0 = g_edge[e];
        int pk1 = g_edge[i1 < e1 ? i1 : e];
        int pk2 = g_edge[i2 < e1 ? i2 : e];
        int pk3 = g_edge[i3 < e1 ? i3 : e];
        if (act) {
            float4 hj0 = *(const float4*)&g_hW[(pk0 & 0xFFFF)*HWP + 376 + 4*q];
            float4 hj1 = *(const float4*)&g_hW[(pk1 & 0xFFFF)*HWP + 376 + 4*q];
            float4 hj2 = *(const float4*)&g_hW[(pk2 & 0xFFFF)*HWP + 376 + 4*q];
            float4 hj3 = *(const float4*)&g_hW[(pk3 & 0xFFFF)*HWP + 376 + 4*q];
            float4 ev0 = *(const float4*)&ec[(pk0 >> 16)*376 + 4*q];
            float4 ev1 = *(const float4*)&ec[(pk1 >> 16)*376 + 4*q];
            float4 ev2 = *(const float4*)&ec[(pk2 >> 16)*376 + 4*q];
            float4 ev3 = *(const float4*)&ec[(pk3 >> 16)*376 + 4*q];
            #define ACCUM(ii, hj, ev)                                        \
                if (ii < e1) {                                               \
                    float m0 = h0 + hj.x + ev.x;                             \
                    float m1 = h1 + hj.y + ev.y;                             \
                    float m2 = h2 + hj.z + ev.z;                             \
                    float m3 = h3 + hj.w + ev.w;                             \
                    s0 += m0; s1 += m1; s2 += m2; s3 += m3;                  \
                    t0 += m0*m0; t1 += m1*m1; t2 += m2*m2; t3 += m3*m3;      \
                    mn0 = fminf(mn0,m0); mn1 = fminf(mn1,m1);                \
                    mn2 = fminf(mn2,m2); mn3 = fminf(mn3,m3);                \
                    mx0 = fmaxf(mx0,m0); mx1 = fmaxf(mx1,m1);                \
                    mx2 = fmaxf(mx2,m2); mx3 = fmaxf(mx3,m3);                \
                }
            ACCUM(e,  hj0, ev0)
            ACCUM(i1, hj1, ev1)
            ACCUM(i2, hj2, ev2)
            ACCUM(i3, hj3, ev3)
            #undef ACCUM
        }
    }

    if (act) {
        float inv = 1.0f / ((cnt > 0) ? (float)cnt : 1.0f);
        float sv[4]  = {s0,s1,s2,s3};
        float tv[4]  = {t0,t1,t2,t3};
        float mnv[4] = {mn0,mn1,mn2,mn3};
        float mxv[4] = {mx0,mx1,mx2,mx3};
        #pragma unroll
        for (int j = 0; j < 4; j++) {
            int c = 4*q + j;
            if (c < TOW*FI) {
                int tw = c / FI, f = c - tw*FI;
                float mean  = sv[j]*inv;
                float mean2 = tv[j]*inv;
                float var = mean2 - mean*mean;
                if (var < 0.f) var = 0.f;
                int b = tw*300 + f;
                aggl[wp][b      ] = mean;
                aggl[wp][b +  75] = (cnt > 0) ? mnv[j] : 0.f;
                aggl[wp][b + 150] = (cnt > 0) ? mxv[j] : 0.f;
                aggl[wp][b + 225] = sqrtf(var + 1e-5f);
            }
        }
    }
    __syncthreads();
    int n0 = blockIdx.x * ENB;
    for (int c = tid; c < 1500; c += 128*ENB) {
        float4 v0 = make_float4(aggl[0][c], aggl[1][c], aggl[2][c], aggl[3][c]);
        float4 v1 = make_float4(aggl[4][c], aggl[5][c], aggl[6][c], aggl[7][c]);
        *(float4*)&aggT[(size_t)c*ATS + n0]     = v0;
        *(float4*)&aggT[(size_t)c*ATS + n0 + 4] = v1;
    }
}

// post GEMM + lin + BN-stat: lane = node (64/block), 15 waves = (tower, k-chunk).
// Weights from packed g_qwP (wave-uniform scalar path). LDS-reduce k-chunks;
// lin; BN shfl + double atomicAdd.
__global__ __launch_bounds__(960) void
k_post3(int l, const float* __restrict__ aggT, const float* __restrict__ qb,
        const float* __restrict__ lw, const float* __restrict__ lb) {
    __shared__ float part[TOW*3*FO*64];   // [tw][kc][g][lane], 57.6 KB
    int lane = threadIdx.x;
    int wv   = __builtin_amdgcn_readfirstlane(threadIdx.y);   // 0..14
    int tw = wv / 3, kc = wv % 3;
    int n0 = blockIdx.x * 64;
    int n  = n0 + lane;

    int cnt = g_rowstart[n+1] - g_rowstart[n];
    float deg = (cnt > 0) ? (float)cnt : 1.0f;
    float amp  = logf(deg + 1.0f) * (1.0f/2.8332133440562162f);
    float iamp = 1.0f / amp;

    const float* A  = aggT + (size_t)(tw*300 + kc*100)*ATS + n0;
    int ltw = l*TOW + tw;
    const float* W0 = g_qwP + ((ltw*3 + 0)*300 + kc*100)*16;
    const float* W1 = g_qwP + ((ltw*3 + 1)*300 + kc*100)*16;
    const float* W2 = g_qwP + ((ltw*3 + 2)*300 + kc*100)*16;

    float a0[FO], a1[FO], a2[FO];
    #pragma unroll
    for (int g = 0; g < FO; g++) { a0[g]=0.f; a1[g]=0.f; a2[g]=0.f; }

    for (int k = 0; k < 100; ++k) {
        float av = A[(size_t)k*ATS + lane];
        const float4* w0 = (const float4*)(W0 + k*16);
        const float4* w1 = (const float4*)(W1 + k*16);
        const float4* w2 = (const float4*)(W2 + k*16);
        float4 q0a=w0[0], q0b=w0[1], q0c=w0[2], q0d=w0[3];
        float4 q1a=w1[0], q1b=w1[1], q1c=w1[2], q1d=w1[3];
        float4 q2a=w2[0], q2b=w2[1], q2c=w2[2], q2d=w2[3];
        a0[0]+=av*q0a.x; a0[1]+=av*q0a.y; a0[2]+=av*q0a.z; a0[3]+=av*q0a.w;
        a0[4]+=av*q0b.x; a0[5]+=av*q0b.y; a0[6]+=av*q0b.z; a0[7]+=av*q0b.w;
        a0[8]+=av*q0c.x; a0[9]+=av*q0c.y; a0[10]+=av*q0c.z; a0[11]+=av*q0c.w;
        a0[12]+=av*q0d.x; a0[13]+=av*q0d.y; a0[14]+=av*q0d.z;
        a1[0]+=av*q1a.x; a1[1]+=av*q1a.y; a1[2]+=av*q1a.z; a1[3]+=av*q1a.w;
        a1[4]+=av*q1b.x; a1[5]+=av*q1b.y; a1[6]+=av*q1b.z; a1[7]+=av*q1b.w;
        a1[8]+=av*q1c.x; a1[9]+=av*q1c.y; a1[10]+=av*q1c.z; a1[11]+=av*q1c.w;
        a1[12]+=av*q1d.x; a1[13]+=av*q1d.y; a1[14]+=av*q1d.z;
        a2[0]+=av*q2a.x; a2[1]+=av*q2a.y; a2[2]+=av*q2a.z; a2[3]+=av*q2a.w;
        a2[4]+=av*q2b.x; a2[5]+=av*q2b.y; a2[6]+=av*q2b.z; a2[7]+=av*q2b.w;
        a2[8]+=av*q2c.x; a2[9]+=av*q2c.y; a2[10]+=av*q2c.z; a2[11]+=av*q2c.w;
        a2[12]+=av*q2d.x; a2[13]+=av*q2d.y; a2[14]+=av*q2d.z;
    }

    float pc[FO];
    #pragma unroll
    for (int g = 0; g < FO; g++) {
        pc[g] = a0[g] + amp*a1[g] + iamp*a2[g];
        part[((tw*3 + kc)*FO + g)*64 + lane] = pc[g];
    }
    __syncthreads();

    if (kc == 0) {
        #pragma unroll
        for (int g = 0; g < FO; g++) {
            float v = qb[tw*FO + g] + pc[g]
                    + part[((tw*3 + 1)*FO + g)*64 + lane]
                    + part[((tw*3 + 2)*FO + g)*64 + lane];
            part[((tw*3 + 0)*FO + g)*64 + lane] = v;
        }
    }
    __syncthreads();

    float res[5];
    #pragma unroll
    for (int cc = 0; cc < 5; cc++) res[cc] = lb[wv*5 + cc];
    for (int f = 0; f < FI; f++) {
        float pv = part[((f/FO)*3*FO + (f%FO))*64 + lane];
        const float* lwf = lw + f*FI + wv*5;
        #pragma unroll
        for (int cc = 0; cc < 5; cc++) res[cc] += pv * lwf[cc];
    }

    #pragma unroll
    for (int cc = 0; cc < 5; cc++) {
        int c = wv*5 + cc;
        float v = res[cc];
        g_hB[n*FI + c] = v;
        float s = v, s2 = v*v;
        #pragma unroll
        for (int d = 1; d < 64; d <<= 1) {
            s  += __shfl_xor(s,  d);
            s2 += __shfl_xor(s2, d);
        }
        if (lane == 0) {
            atomicAdd(&g_bns1[c], (double)s);
            atomicAdd(&g_bns2[c], (double)s2);
        }
    }
}

__global__ void k_poolzero() {
    int i = blockIdx.x * blockDim.x + threadIdx.x;
    if (i < NG*FI) g_pool[i] = 0.f;
}

// pool with fused BN+ReLU of layer 3 (mu/rsig recomputed from sums)
__global__ void k_pool(const int* __restrict__ batch, const float* __restrict__ gamma,
                       const float* __restrict__ beta) {
    int i = blockIdx.x * blockDim.x + threadIdx.x;
    if (i < N_NODES*FI) {
        int n = i / FI, c = i % FI;
        double mud  = g_bns1[c] * (1.0/N_NODES);
        double vard = g_bns2[c] * (1.0/N_NODES) - mud*mud;
        if (vard < 0.0) vard = 0.0;
        float mu   = (float)mud;
        float rsig = (float)(1.0 / sqrt(vard + 1e-5));
        float v = (g_hB[i] - mu) * rsig * gamma[c] + beta[c];
        v = v > 0.f ? v : 0.f;
        atomicAdd(&g_pool[batch[n]*FI + c], v);
    }
}

__global__ void k_mlp(const float* __restrict__ w1, const float* __restrict__ b1,
                      const float* __restrict__ w2, const float* __restrict__ b2,
                      const float* __restrict__ w3, const float* __restrict__ b3,
                      float* __restrict__ out) {
    __shared__ float gin[FI], h1[50], h2[25];
    int gi = blockIdx.x;
    int t = threadIdx.x;
    if (t < FI) gin[t] = g_pool[gi*FI + t];
    __syncthreads();
    if (t < 50) {
        float s = b1[t];
        for (int f = 0; f < FI; f++) s += gin[f] * w1[f*50 + t];
        h1[t] = s > 0.f ? s : 0.f;
    }
    __syncthreads();
    if (t < 25) {
        float s = b2[t];
        for (int f = 0; f < 50; f++) s += h1[f] * w2[f*25 + t];
        h2[t] = s > 0.f ? s : 0.f;
    }
    __syncthreads();
    if (t == 0) {
        float s = b3[0];
        for (int f = 0; f < 25; f++) s += h2[f] * w3[f];
        out[gi] = s;
    }
}

extern "C" void kernel_launch(void* const* d_in, const int* in_sizes, int n_in,
                              void* d_out, int out_size, void* d_ws, size_t ws_size,
                              hipStream_t stream) {
    const int*   x          = (const int*)  d_in[0];
    const int*   edge_index = (const int*)  d_in[1];
    const int*   edge_attr  = (const int*)  d_in[2];
    const int*   batch      = (const int*)  d_in[3];
    const float* node_emb   = (const float*)d_in[4];
    const float* edge_emb   = (const float*)d_in[5];
    const float* edge_enc_w = (const float*)d_in[6];
    const float* edge_enc_b = (const float*)d_in[7];
    const float* pre_w      = (const float*)d_in[8];
    const float* pre_b      = (const float*)d_in[9];
    const float* post_w     = (const float*)d_in[10];
    const float* post_b     = (const float*)d_in[11];
    const float* lin_w      = (const float*)d_in[12];
    const float* lin_b      = (const float*)d_in[13];
    const float* bn_gamma   = (const float*)d_in[14];
    const float* bn_beta    = (const float*)d_in[15];
    const float* mlp_w1     = (const float*)d_in[16];
    const float* mlp_b1     = (const float*)d_in[17];
    const float* mlp_w2     = (const float*)d_in[18];
    const float* mlp_b2     = (const float*)d_in[19];
    const float* mlp_w3     = (const float*)d_in[20];
    const float* mlp_b3     = (const float*)d_in[21];
    float* out  = (float*)d_out;
    float* aggT = (float*)d_ws;     // 1500 x ATS floats = 98.4 MB (channel-major)

    const int* src = edge_index;
    const int* dst = edge_index + N_EDGES;

    k_embed<<<(N_NODES*FI + 255)/256, 256, 0, stream>>>(x, node_emb);
    k_zerodeg<<<(N_NODES + 255)/256, 256, 0, stream>>>();
    k_hist<<<(N_EDGES + 255)/256, 256, 0, stream>>>(dst);
    k_scan<<<1, 1024, 0, stream>>>();
    k_scatter<<<(N_EDGES + 255)/256, 256, 0, stream>>>(src, dst, edge_attr);
    k_wq<<<(NL*TOW*900*FO + 255)/256, 256, 0, stream>>>(post_w);
    k_ec<<<NL, 512, 0, stream>>>(edge_emb, edge_enc_w, edge_enc_b, pre_w, pre_b);

    for (int l = 0; l < NL; l++) {
        const float* pw  = pre_w  + l*TOW*(3*FI)*FI;
        const float* qb  = post_b + l*TOW*FO;
        const float* lw  = lin_w  + l*(TOW*FO)*(TOW*FO);
        const float* lb  = lin_b  + l*TOW*FO;
        const float* gamP = bn_gamma + (l > 0 ? (l-1)*FI : 0);
        const float* betP = bn_beta  + (l > 0 ? (l-1)*FI : 0);

        k_hw<<<N_NODES/NPB, 256, 0, stream>>>(pw, gamP, betP, l == 0 ? 1 : 0);
        k_edge<<<N_NODES/ENB, 128*ENB, 0, stream>>>(l, aggT);
        k_post3<<<dim3(N_NODES/64), dim3(64,15), 0, stream>>>(l, aggT, qb, lw, lb);
    }

    k_poolzero<<<(NG*FI + 255)/256, 256, 0, stream>>>();
    k_pool<<<(N_NODES*FI + 255)/256, 256, 0, stream>>>(batch, bn_gamma + 3*FI, bn_beta + 3*FI);
    k_mlp<<<NG, 128, 0, stream>>>(mlp_w1, mlp_b1, mlp_w2, mlp_b2, mlp_w3, mlp_b3, out);
}

// Round 18
// 1107.503 us; speedup vs baseline: 2.2316x; 2.2316x over previous
//
#include <hip/hip_runtime.h>
#include <math.h>

#define N_NODES 16384
#define N_EDGES 262144
#define TOW 5
#define FI 75            // F_IN
#define FO 15            // F_OUT
#define DE 50
#define NL 4
#define NG 256
#define HWP 752          // padded node stride: [hWi 0..374][pad][hWj 376..750][pad]
#define ATS 16400        // aggT row stride in floats (16384 + 16: breaks 64KB aliasing)
#define ENB 8            // nodes per k_edge block (one 128-lane wave-pair each)

static __device__ __attribute__((aligned(16))) float g_hA[N_NODES*FI];
static __device__ __attribute__((aligned(16))) float g_hB[N_NODES*FI];
static __device__ __attribute__((aligned(16))) float g_hW[N_NODES*HWP];
static __device__ __attribute__((aligned(16))) float g_ec[NL*4*376];
static __device__ __attribute__((aligned(16))) float g_qwP[NL*TOW*3*300*16]; // padded repack
static __device__ int    g_deg[N_NODES];
static __device__ int    g_rowstart[N_NODES+1];
static __device__ int    g_cursor[N_NODES];
static __device__ int    g_edge[N_EDGES];
static __device__ double g_bns1[FI];
static __device__ double g_bns2[FI];
static __device__ float  g_pool[NG*FI];

__global__ void k_embed(const int* __restrict__ x, const float* __restrict__ node_emb) {
    int i = blockIdx.x * blockDim.x + threadIdx.x;
    if (i < N_NODES*FI) {
        int n = i / FI, f = i % FI;
        g_hA[i] = node_emb[x[n]*FI + f];
    }
}

__global__ void k_zerodeg() {
    int i = blockIdx.x * blockDim.x + threadIdx.x;
    if (i < N_NODES) g_deg[i] = 0;
}

__global__ void k_hist(const int* __restrict__ dst) {
    int e = blockIdx.x * blockDim.x + threadIdx.x;
    if (e < N_EDGES) atomicAdd(&g_deg[dst[e]], 1);
}

__global__ void k_scan() {
    __shared__ int part[1024];
    int t = threadIdx.x;
    int base = t * 16;
    int loc[16];
    int s = 0;
    #pragma unroll
    for (int i = 0; i < 16; i++) { loc[i] = s; s += g_deg[base + i]; }
    part[t] = s;
    __syncthreads();
    for (int off = 1; off < 1024; off <<= 1) {
        int v = 0;
        if (t >= off) v = part[t - off];
        __syncthreads();
        if (t >= off) part[t] += v;
        __syncthreads();
    }
    int excl = (t == 0) ? 0 : part[t - 1];
    #pragma unroll
    for (int i = 0; i < 16; i++) {
        g_rowstart[base + i] = excl + loc[i];
        g_cursor[base + i]   = excl + loc[i];
    }
    if (t == 1023) g_rowstart[N_NODES] = part[1023];
}

__global__ void k_scatter(const int* __restrict__ src, const int* __restrict__ dst,
                          const int* __restrict__ attr) {
    int e = blockIdx.x * blockDim.x + threadIdx.x;
    if (e < N_EDGES) {
        int d = dst[e];
        int pos = atomicAdd(&g_cursor[d], 1);
        g_edge[pos] = src[e] | (attr[e] << 16);
    }
}

// one-time repack of post_w into padded 16-float rows:
// g_qwP[(( (l*5+tw)*3 + s )*300 + k)*16 + g]
__global__ void k_wq(const float* __restrict__ post_w) {
    int i = blockIdx.x * blockDim.x + threadIdx.x;
    if (i < NL*TOW*900*FO) {
        int g = i % FO;
        int r = i / FO;
        int f = r % 900;
        int lt = r / 900;          // l*5+tw
        int s = f / 300, k = f % 300;
        g_qwP[((lt*3 + s)*300 + k)*16 + g] = post_w[i];
    }
}

// all-layer edge contribution tables: g_ec[l][a][376]
__global__ void k_ec(const float* __restrict__ edge_emb, const float* __restrict__ edge_enc_w,
                     const float* __restrict__ edge_enc_b, const float* __restrict__ pre_w,
                     const float* __restrict__ pre_b) {
    int l = blockIdx.x;
    const float* eew = edge_enc_w + l*DE*FI;
    const float* eeb = edge_enc_b + l*FI;
    const float* pw  = pre_w + l*TOW*3*FI*FI;
    const float* pb  = pre_b + l*TOW*FI;
    __shared__ float e_enc[4*FI];
    int t = threadIdx.x;
    if (t < 4*FI) {
        int a = t / FI, f = t % FI;
        float s = eeb[f];
        for (int d = 0; d < DE; d++) s += edge_emb[a*DE + d] * eew[d*FI + f];
        e_enc[t] = s;
    }
    __syncthreads();
    for (int o = t; o < 4*376; o += blockDim.x) {
        int a = o / 376;
        int r = o % 376;
        float s = 0.f;
        if (r < TOW*FI) {
            int tw = r / FI, g = r % FI;
            s = pb[tw*FI + g];
            const float* W = pw + (tw*(3*FI) + 2*FI)*FI + g;
            for (int f = 0; f < FI; f++) s += e_enc[a*FI + f] * W[f*FI];
        }
        g_ec[l*1504 + o] = s;
    }
}

// node transform; BN+ReLU of previous layer fused, recomputing mu/rsig from sums
#define NPB 8
__global__ void k_hw(const float* __restrict__ pw, const float* __restrict__ gamma,
                     const float* __restrict__ beta, int first) {
    __shared__ float hsh[NPB*FI];
    int n0 = blockIdx.x * NPB;
    int tid = threadIdx.x;
    for (int i = tid; i < NPB*FI; i += blockDim.x) {
        int idx = (n0 + i/FI)*FI + (i % FI);
        float v;
        if (first) {
            v = g_hA[idx];
        } else {
            int c = i % FI;
            double mud  = g_bns1[c] * (1.0/N_NODES);
            double vard = g_bns2[c] * (1.0/N_NODES) - mud*mud;
            if (vard < 0.0) vard = 0.0;
            float mu   = (float)mud;
            float rsig = (float)(1.0 / sqrt(vard + 1e-5));
            v = (g_hB[idx] - mu) * rsig * gamma[c] + beta[c];
            v = v > 0.f ? v : 0.f;
        }
        hsh[i] = v;
    }
    __syncthreads();
    for (int o = tid; o < 2*TOW*FI; o += blockDim.x) {
        int half = o / (TOW*FI);
        int r = o % (TOW*FI);
        int tw = r / FI, g = r % FI;
        const float* W = pw + (tw*(3*FI) + half*FI)*FI + g;
        float acc[NPB];
        #pragma unroll
        for (int nn = 0; nn < NPB; nn++) acc[nn] = 0.f;
        for (int f = 0; f < FI; f++) {
            float w = W[f*FI];
            #pragma unroll
            for (int nn = 0; nn < NPB; nn++) acc[nn] += hsh[nn*FI + f] * w;
        }
        #pragma unroll
        for (int nn = 0; nn < NPB; nn++)
            g_hW[(n0+nn)*HWP + half*376 + r] = acc[nn];
    }
}

// per-node edge aggregation: one 128-lane wave-pair per node, ENB=8 nodes/block
// (1024 threads). Register accumulate; finalize into LDS tile; transpose-write
// channel-major aggT as 32B runs (normal stores -> L2 write-combining).
__global__ __launch_bounds__(128*ENB) void k_edge(int l, float* __restrict__ aggT) {
    __shared__ float aggl[ENB][1504];
    int tid = threadIdx.x;
    if (blockIdx.x == 0 && tid < FI) { g_bns1[tid] = 0.0; g_bns2[tid] = 0.0; }
    int wp  = tid >> 7;
    int q   = tid & 127;
    int n   = blockIdx.x * ENB + wp;
    bool act = q < 94;
    const float* ec = g_ec + l*1504;
    int e0 = g_rowstart[n], e1 = g_rowstart[n+1];
    int cnt = e1 - e0;

    float s0=0.f,s1=0.f,s2=0.f,s3=0.f;
    float t0=0.f,t1=0.f,t2=0.f,t3=0.f;
    float mn0=1e30f,mn1=1e30f,mn2=1e30f,mn3=1e30f;
    float mx0=-1e30f,mx1=-1e30f,mx2=-1e30f,mx3=-1e30f;
    float h0=0.f,h1=0.f,h2=0.f,h3=0.f;
    if (act) {
        float4 hv = *(const float4*)&g_hW[n*HWP + 4*q];
        h0=hv.x; h1=hv.y; h2=hv.z; h3=hv.w;
    }

    for (int e = e0; e < e1; e += 4) {
        int i1 = e+1, i2 = e+2, i3 = e+3;
        int pk0 = g_edge[e];
        int pk1 = g_edge[i1 < e1 ? i1 : e];
        int pk2 = g_edge[i2 < e1 ? i2 : e];
        int pk3 = g_edge[i3 < e1 ? i3 : e];
        if (act) {
            float4 hj0 = *(const float4*)&g_hW[(pk0 & 0xFFFF)*HWP + 376 + 4*q];
            float4 hj1 = *(const float4*)&g_hW[(pk1 & 0xFFFF)*HWP + 376 + 4*q];
            float4 hj2 = *(const float4*)&g_hW[(pk2 & 0xFFFF)*HWP + 376 + 4*q];
            float4 hj3 = *(const float4*)&g_hW[(pk3 & 0xFFFF)*HWP + 376 + 4*q];
            float4 ev0 = *(const float4*)&ec[(pk0 >> 16)*376 + 4*q];
            float4 ev1 = *(const float4*)&ec[(pk1 >> 16)*376 + 4*q];
            float4 ev2 = *(const float4*)&ec[(pk2 >> 16)*376 + 4*q];
            float4 ev3 = *(const float4*)&ec[(pk3 >> 16)*376 + 4*q];
            #define ACCUM(ii, hj, ev)                                        \
                if (ii < e1) {                                               \
                    float m0 = h0 + hj.x + ev.x;                             \
                    float m1 = h1 + hj.y + ev.y;                             \
                    float m2 = h2 + hj.z + ev.z;                             \
                    float m3 = h3 + hj.w + ev.w;                             \
                    s0 += m0; s1 += m1; s2 += m2; s3 += m3;                  \
                    t0 += m0*m0; t1 += m1*m1; t2 += m2*m2; t3 += m3*m3;      \
                    mn0 = fminf(mn0,m0); mn1 = fminf(mn1,m1);                \
                    mn2 = fminf(mn2,m2); mn3 = fminf(mn3,m3);                \
                    mx0 = fmaxf(mx0,m0); mx1 = fmaxf(mx1,m1);                \
                    mx2 = fmaxf(mx2,m2); mx3 = fmaxf(mx3,m3);                \
                }
            ACCUM(e,  hj0, ev0)
            ACCUM(i1, hj1, ev1)
            ACCUM(i2, hj2, ev2)
            ACCUM(i3, hj3, ev3)
            #undef ACCUM
        }
    }

    if (act) {
        float inv = 1.0f / ((cnt > 0) ? (float)cnt : 1.0f);
        float sv[4]  = {s0,s1,s2,s3};
        float tv[4]  = {t0,t1,t2,t3};
        float mnv[4] = {mn0,mn1,mn2,mn3};
        float mxv[4] = {mx0,mx1,mx2,mx3};
        #pragma unroll
        for (int j = 0; j < 4; j++) {
            int c = 4*q + j;
            if (c < TOW*FI) {
                int tw = c / FI, f = c - tw*FI;
                float mean  = sv[j]*inv;
                float mean2 = tv[j]*inv;
                float var = mean2 - mean*mean;
                if (var < 0.f) var = 0.f;
                int b = tw*300 + f;
                aggl[wp][b      ] = mean;
                aggl[wp][b +  75] = (cnt > 0) ? mnv[j] : 0.f;
                aggl[wp][b + 150] = (cnt > 0) ? mxv[j] : 0.f;
                aggl[wp][b + 225] = sqrtf(var + 1e-5f);
            }
        }
    }
    __syncthreads();
    int n0 = blockIdx.x * ENB;
    for (int c = tid; c < 1500; c += 128*ENB) {
        float4 v0 = make_float4(aggl[0][c], aggl[1][c], aggl[2][c], aggl[3][c]);
        float4 v1 = make_float4(aggl[4][c], aggl[5][c], aggl[6][c], aggl[7][c]);
        *(float4*)&aggT[(size_t)c*ATS + n0]     = v0;
        *(float4*)&aggT[(size_t)c*ATS + n0 + 4] = v1;
    }
}

// post GEMM + lin + BN-stat: lane = node (64/block), 15 waves = (tower, k-chunk).
// Weights from packed g_qwP (wave-uniform scalar path). LDS-reduce k-chunks;
// lin; BN shfl + double atomicAdd.
__global__ __launch_bounds__(960) void
k_post3(int l, const float* __restrict__ aggT, const float* __restrict__ qb,
        const float* __restrict__ lw, const float* __restrict__ lb) {
    __shared__ float part[TOW*3*FO*64];   // [tw][kc][g][lane], 57.6 KB
    int lane = threadIdx.x;
    int wv   = __builtin_amdgcn_readfirstlane(threadIdx.y);   // 0..14
    int tw = wv / 3, kc = wv % 3;
    int n0 = blockIdx.x * 64;
    int n  = n0 + lane;

    int cnt = g_rowstart[n+1] - g_rowstart[n];
    float deg = (cnt > 0) ? (float)cnt : 1.0f;
    float amp  = logf(deg + 1.0f) * (1.0f/2.8332133440562162f);
    float iamp = 1.0f / amp;

    const float* A  = aggT + (size_t)(tw*300 + kc*100)*ATS + n0;
    int ltw = l*TOW + tw;
    const float* W0 = g_qwP + ((ltw*3 + 0)*300 + kc*100)*16;
    const float* W1 = g_qwP + ((ltw*3 + 1)*300 + kc*100)*16;
    const float* W2 = g_qwP + ((ltw*3 + 2)*300 + kc*100)*16;

    float a0[FO], a1[FO], a2[FO];
    #pragma unroll
    for (int g = 0; g < FO; g++) { a0[g]=0.f; a1[g]=0.f; a2[g]=0.f; }

    for (int k = 0; k < 100; ++k) {
        float av = A[(size_t)k*ATS + lane];
        const float4* w0 = (const float4*)(W0 + k*16);
        const float4* w1 = (const float4*)(W1 + k*16);
        const float4* w2 = (const float4*)(W2 + k*16);
        float4 q0a=w0[0], q0b=w0[1], q0c=w0[2], q0d=w0[3];
        float4 q1a=w1[0], q1b=w1[1], q1c=w1[2], q1d=w1[3];
        float4 q2a=w2[0], q2b=w2[1], q2c=w2[2], q2d=w2[3];
        a0[0]+=av*q0a.x; a0[1]+=av*q0a.y; a0[2]+=av*q0a.z; a0[3]+=av*q0a.w;
        a0[4]+=av*q0b.x; a0[5]+=av*q0b.y; a0[6]+=av*q0b.z; a0[7]+=av*q0b.w;
        a0[8]+=av*q0c.x; a0[9]+=av*q0c.y; a0[10]+=av*q0c.z; a0[11]+=av*q0c.w;
        a0[12]+=av*q0d.x; a0[13]+=av*q0d.y; a0[14]+=av*q0d.z;
        a1[0]+=av*q1a.x; a1[1]+=av*q1a.y; a1[2]+=av*q1a.z; a1[3]+=av*q1a.w;
        a1[4]+=av*q1b.x; a1[5]+=av*q1b.y; a1[6]+=av*q1b.z; a1[7]+=av*q1b.w;
        a1[8]+=av*q1c.x; a1[9]+=av*q1c.y; a1[10]+=av*q1c.z; a1[11]+=av*q1c.w;
        a1[12]+=av*q1d.x; a1[13]+=av*q1d.y; a1[14]+=av*q1d.z;
        a2[0]+=av*q2a.x; a2[1]+=av*q2a.y; a2[2]+=av*q2a.z; a2[3]+=av*q2a.w;
        a2[4]+=av*q2b.x; a2[5]+=av*q2b.y; a2[6]+=av*q2b.z; a2[7]+=av*q2b.w;
        a2[8]+=av*q2c.x; a2[9]+=av*q2c.y; a2[10]+=av*q2c.z; a2[11]+=av*q2c.w;
        a2[12]+=av*q2d.x; a2[13]+=av*q2d.y; a2[14]+=av*q2d.z;
    }

    float pc[FO];
    #pragma unroll
    for (int g = 0; g < FO; g++) {
        pc[g] = a0[g] + amp*a1[g] + iamp*a2[g];
        part[((tw*3 + kc)*FO + g)*64 + lane] = pc[g];
    }
    __syncthreads();

    if (kc == 0) {
        #pragma unroll
        for (int g = 0; g < FO; g++) {
            float v = qb[tw*FO + g] + pc[g]
                    + part[((tw*3 + 1)*FO + g)*64 + lane]
                    + part[((tw*3 + 2)*FO + g)*64 + lane];
            part[((tw*3 + 0)*FO + g)*64 + lane] = v;
        }
    }
    __syncthreads();

    float res[5];
    #pragma unroll
    for (int cc = 0; cc < 5; cc++) res[cc] = lb[wv*5 + cc];
    for (int f = 0; f < FI; f++) {
        float pv = part[((f/FO)*3*FO + (f%FO))*64 + lane];
        const float* lwf = lw + f*FI + wv*5;
        #pragma unroll
        for (int cc = 0; cc < 5; cc++) res[cc] += pv * lwf[cc];
    }

    #pragma unroll
    for (int cc = 0; cc < 5; cc++) {
        int c = wv*5 + cc;
        float v = res[cc];
        g_hB[n*FI + c] = v;
        float s = v, s2 = v*v;
        #pragma unroll
        for (int d = 1; d < 64; d <<= 1) {
            s  += __shfl_xor(s,  d);
            s2 += __shfl_xor(s2, d);
        }
        if (lane == 0) {
            atomicAdd(&g_bns1[c], (double)s);
            atomicAdd(&g_bns2[c], (double)s2);
        }
    }
}

__global__ void k_poolzero() {
    int i = blockIdx.x * blockDim.x + threadIdx.x;
    if (i < NG*FI) g_pool[i] = 0.f;
}

// pool with fused BN+ReLU of layer 3 (mu/rsig recomputed from sums)
__global__ void k_pool(const int* __restrict__ batch, const float* __restrict__ gamma,
                       const float* __restrict__ beta) {
    int i = blockIdx.x * blockDim.x + threadIdx.x;
    if (i < N_NODES*FI) {
        int n = i / FI, c = i % FI;
        double mud  = g_bns1[c] * (1.0/N_NODES);
        double vard = g_bns2[c] * (1.0/N_NODES) - mud*mud;
        if (vard < 0.0) vard = 0.0;
        float mu   = (float)mud;
        float rsig = (float)(1.0 / sqrt(vard + 1e-5));
        float v = (g_hB[i] - mu) * rsig * gamma[c] + beta[c];
        v = v > 0.f ? v : 0.f;
        atomicAdd(&g_pool[batch[n]*FI + c], v);
    }
}

__global__ void k_mlp(const float* __restrict__ w1, const float* __restrict__ b1,
                      const float* __restrict__ w2, const float* __restrict__ b2,
                      const float* __restrict__ w3, const float* __restrict__ b3,
                      float* __restrict__ out) {
    __shared__ float gin[FI], h1[50], h2[25];
    int gi = blockIdx.x;
    int t = threadIdx.x;
    if (t < FI) gin[t] = g_pool[gi*FI + t];
    __syncthreads();
    if (t < 50) {
        float s = b1[t];
        for (int f = 0; f < FI; f++) s += gin[f] * w1[f*50 + t];
        h1[t] = s > 0.f ? s : 0.f;
    }
    __syncthreads();
    if (t < 25) {
        float s = b2[t];
        for (int f = 0; f < 50; f++) s += h1[f] * w2[f*25 + t];
        h2[t] = s > 0.f ? s : 0.f;
    }
    __syncthreads();
    if (t == 0) {
        float s = b3[0];
        for (int f = 0; f < 25; f++) s += h2[f] * w3[f];
        out[gi] = s;
    }
}

extern "C" void kernel_launch(void* const* d_in, const int* in_sizes, int n_in,
                              void* d_out, int out_size, void* d_ws, size_t ws_size,
                              hipStream_t stream) {
    const int*   x          = (const int*)  d_in[0];
    const int*   edge_index = (const int*)  d_in[1];
    const int*   edge_attr  = (const int*)  d_in[2];
    const int*   batch      = (const int*)  d_in[3];
    const float* node_emb   = (const float*)d_in[4];
    const float* edge_emb   = (const float*)d_in[5];
    const float* edge_enc_w = (const float*)d_in[6];
    const float* edge_enc_b = (const float*)d_in[7];
    const float* pre_w      = (const float*)d_in[8];
    const float* pre_b      = (const float*)d_in[9];
    const float* post_w     = (const float*)d_in[10];
    const float* post_b     = (const float*)d_in[11];
    const float* lin_w      = (const float*)d_in[12];
    const float* lin_b      = (const float*)d_in[13];
    const float* bn_gamma   = (const float*)d_in[14];
    const float* bn_beta    = (const float*)d_in[15];
    const float* mlp_w1     = (const float*)d_in[16];
    const float* mlp_b1     = (const float*)d_in[17];
    const float* mlp_w2     = (const float*)d_in[18];
    const float* mlp_b2     = (const float*)d_in[19];
    const float* mlp_w3     = (const float*)d_in[20];
    const float* mlp_b3     = (const float*)d_in[21];
    float* out  = (float*)d_out;
    float* aggT = (float*)d_ws;     // 1500 x ATS floats = 98.4 MB (channel-major)

    const int* src = edge_index;
    const int* dst = edge_index + N_EDGES;

    k_embed<<<(N_NODES*FI + 255)/256, 256, 0, stream>>>(x, node_emb);
    k_zerodeg<<<(N_NODES + 255)/256, 256, 0, stream>>>();
    k_hist<<<(N_EDGES + 255)/256, 256, 0, stream>>>(dst);
    k_scan<<<1, 1024, 0, stream>>>();
    k_scatter<<<(N_EDGES + 255)/256, 256, 0, stream>>>(src, dst, edge_attr);
    k_wq<<<(NL*TOW*900*FO + 255)/256, 256, 0, stream>>>(post_w);
    k_ec<<<NL, 512, 0, stream>>>(edge_emb, edge_enc_w, edge_enc_b, pre_w, pre_b);

    for (int l = 0; l < NL; l++) {
        const float* pw  = pre_w  + l*TOW*(3*FI)*FI;
        const float* qb  = post_b + l*TOW*FO;
        const float* lw  = lin_w  + l*(TOW*FO)*(TOW*FO);
        const float* lb  = lin_b  + l*TOW*FO;
        const float* gamP = bn_gamma + (l > 0 ? (l-1)*FI : 0);
        const float* betP = bn_beta  + (l > 0 ? (l-1)*FI : 0);

        k_hw<<<N_NODES/NPB, 256, 0, stream>>>(pw, gamP, betP, l == 0 ? 1 : 0);
        k_edge<<<N_NODES/ENB, 128*ENB, 0, stream>>>(l, aggT);
        k_post3<<<dim3(N_NODES/64), dim3(64,15), 0, stream>>>(l, aggT, qb, lw, lb);
    }

    k_poolzero<<<(NG*FI + 255)/256, 256, 0, stream>>>();
    k_pool<<<(N_NODES*FI + 255)/256, 256, 0, stream>>>(batch, bn_gamma + 3*FI, bn_beta + 3*FI);
    k_mlp<<<NG, 128, 0, stream>>>(mlp_w1, mlp_b1, mlp_w2, mlp_b2, mlp_w3, mlp_b3, out);
}